// Round 11
// baseline (155.101 us; speedup 1.0000x reference)
//
#include <hip/hip_runtime.h>
#include <math.h>

#define NROWS 16384   // B*M
#define NN 32
#define NC 256
#define ND 128
#define RB 4          // rows per block (4 waves x 1 row in stream phase)
#define LNEPS 1e-5f
#define SCALE 0.08838834764831845f  // 1/sqrt(128)

typedef float vfloat4 __attribute__((ext_vector_type(4)));

// workspace float offsets
#define OFF_MT   0                      // Mt[c*256+j] = M''[j,c]   (65536)
#define OFF_UVEC 65536                  // uvec_j = sum_c M''[j,c]  (256)
#define OFF_VV   65792                  // vv_j                     (256)
#define OFF_M1   66048                  // m1_c = sum_j M''[j,c]    (256)
#define OFF_WG   66304                  // wg_c = qgamma_c * w_c    (256)
#define OFF_SCAL 66560                  // [sgw, sbw_full, su, svv] (8)

// Sum across each 16-lane row via DPP row_ror (VALU, ~4cy/step; no DS pipe).
__device__ __forceinline__ float red16(float v) {
    int t;
    t = __builtin_amdgcn_update_dpp(0, __float_as_int(v), 0x121, 0xf, 0xf, false); // row_ror:1
    v += __int_as_float(t);
    t = __builtin_amdgcn_update_dpp(0, __float_as_int(v), 0x122, 0xf, 0xf, false); // row_ror:2
    v += __int_as_float(t);
    t = __builtin_amdgcn_update_dpp(0, __float_as_int(v), 0x124, 0xf, 0xf, false); // row_ror:4
    v += __int_as_float(t);
    t = __builtin_amdgcn_update_dpp(0, __float_as_int(v), 0x128, 0xf, 0xf, false); // row_ror:8
    v += __int_as_float(t);
    return v;
}

// ---------------- K0a: M''[j,c] = kg_j*qg_c*sum_d Wk[j,d]Wq[c,d]; uvec, vv(part) ----------------
__global__ __launch_bounds__(256)
void ca_prep_a(const float* __restrict__ Wq, const float* __restrict__ Wk,
               const float* __restrict__ qg, const float* __restrict__ qb,
               const float* __restrict__ kg, float* __restrict__ ws) {
    __shared__ __align__(16) float wkrow[ND];
    __shared__ float red[8];
    const int j = blockIdx.x;
    const int c = threadIdx.x;
    const int lane = c & 63, wv = c >> 6;
    if (c < ND / 4) *(float4*)(wkrow + 4 * c) = *(const float4*)(Wk + j * ND + 4 * c);
    __syncthreads();
    float m = 0.f;
    #pragma unroll 8
    for (int d = 0; d < ND; d += 4) {
        const float4 wq4 = *(const float4*)(Wq + c * ND + d);
        const float4 wk4 = *(const float4*)(wkrow + d);
        m += wq4.x * wk4.x + wq4.y * wk4.y + wq4.z * wk4.z + wq4.w * wk4.w;
    }
    const float kgj = kg[j];
    const float mpp = kgj * qg[c] * m;     // M''[j,c]
    ws[OFF_MT + c * NC + j] = mpp;         // transposed store
    float a = red16(mpp), b = red16(kgj * m * qb[c]);
    a += __shfl_xor(a, 16, 64); b += __shfl_xor(b, 16, 64);
    a += __shfl_xor(a, 32, 64); b += __shfl_xor(b, 32, 64);
    if (lane == 0) { red[wv] = a; red[4 + wv] = b; }
    __syncthreads();
    if (c == 0) {
        ws[OFF_UVEC + j] = red[0] + red[1] + red[2] + red[3];
        ws[OFF_VV + j]   = red[4] + red[5] + red[6] + red[7];
    }
}

// ---------------- K0b: m1, h, vv += kg*(Wk bq), wg, scalars ----------------
__global__ __launch_bounds__(256)
void ca_prep_b(const float* __restrict__ Wq, const float* __restrict__ Wk,
               const float* __restrict__ qg, const float* __restrict__ qb,
               const float* __restrict__ kg, const float* __restrict__ kb,
               const float* __restrict__ bq, const float* __restrict__ bk,
               float* __restrict__ ws) {
    __shared__ float h[ND];
    __shared__ float htmp[2][ND];
    __shared__ float red[16];
    const int t = threadIdx.x, lane = t & 63, wv = t >> 6;
    // m1_c = sum_j Mt[c*NC + j]  (contiguous per thread, L2-hot)
    {
        float s = 0.f;
        const float* mrow = ws + OFF_MT + t * NC;
        #pragma unroll 8
        for (int j2 = 0; j2 < NC; j2 += 4) {
            const float4 m4 = *(const float4*)(mrow + j2);
            s += (m4.x + m4.y) + (m4.z + m4.w);
        }
        ws[OFF_M1 + t] = s;
    }
    // h_d = bk_d + sum_j Wk[j,d]*kb_j  (two half-sums)
    {
        const int d = t & (ND - 1), half = t >> 7;
        float s = 0.f;
        #pragma unroll 8
        for (int j = half * 128; j < half * 128 + 128; ++j) s += Wk[j * ND + d] * kb[j];
        htmp[half][d] = s;
    }
    __syncthreads();
    if (t < ND) h[t] = bk[t] + htmp[0][t] + htmp[1][t];
    __syncthreads();
    // vv[j] += kg_j*(Wk bq)_j
    float vvj;
    {
        float s = 0.f;
        #pragma unroll 8
        for (int d = 0; d < ND; d += 4) {
            const float4 w4 = *(const float4*)(Wk + t * ND + d);
            const float4 b4 = *(const float4*)(bq + d);
            s += w4.x * b4.x + w4.y * b4.y + w4.z * b4.z + w4.w * b4.w;
        }
        vvj = ws[OFF_VV + t] + kg[t] * s;
        ws[OFF_VV + t] = vvj;
    }
    // w_c = Wq[c,:].h ; wg, scalar sums
    float w = 0.f;
    #pragma unroll 8
    for (int d = 0; d < ND; d += 4) {
        const float4 w4 = *(const float4*)(Wq + t * ND + d);
        w += w4.x * h[d] + w4.y * h[d + 1] + w4.z * h[d + 2] + w4.w * h[d + 3];
    }
    ws[OFF_WG + t] = qg[t] * w;
    float r0 = qg[t] * w;
    float r1 = qb[t] * w + ((t < ND) ? bq[t] * h[t] : 0.f);
    float r2 = ws[OFF_UVEC + t];
    float r3 = vvj;
    r0 = red16(r0); r1 = red16(r1); r2 = red16(r2); r3 = red16(r3);
    #pragma unroll
    for (int s = 16; s < 64; s <<= 1) {
        r0 += __shfl_xor(r0, s, 64); r1 += __shfl_xor(r1, s, 64);
        r2 += __shfl_xor(r2, s, 64); r3 += __shfl_xor(r3, s, 64);
    }
    if (lane == 0) { red[wv] = r0; red[4 + wv] = r1; red[8 + wv] = r2; red[12 + wv] = r3; }
    __syncthreads();
    if (t == 0) {
        ws[OFF_SCAL + 0] = red[0] + red[1] + red[2] + red[3];
        ws[OFF_SCAL + 1] = red[4] + red[5] + red[6] + red[7];
        ws[OFF_SCAL + 2] = red[8] + red[9] + red[10] + red[11];
        ws[OFF_SCAL + 3] = red[12] + red[13] + red[14] + red[15];
    }
}

// ---------------- Fused main (hi-occupancy): 20KB LDS, <=64 VGPR target ----------------
__global__ __launch_bounds__(256, 8)
void ca_main(const float* __restrict__ x, const float* __restrict__ y,
             const float* __restrict__ z, const float* __restrict__ ws,
             float* __restrict__ out) {
    __shared__ __align__(16) float xs[RB * NC];       // 4 KB: x rows; reused for gp after phase 2
    __shared__ __align__(16) float tp[4 * RB * NC];   // 16 KB: GEMV partials
    const int tid = threadIdx.x;
    const int lane = tid & 63;
    const int wv = tid >> 6;          // wave wv owns row wv
    const int row0 = blockIdx.x * RB;

    float mu_r, rstd_r, cst_r, sg_r;

    // ---- Phase 0: stats on own row + stage x to LDS ----
    {
        const float4 wg4 = *(const float4*)(ws + OFF_WG + 4 * lane);
        const float4 m14 = *(const float4*)(ws + OFF_M1 + 4 * lane);
        const float s0 = ws[OFF_SCAL + 0], s1c = ws[OFF_SCAL + 1];
        const float s2c = ws[OFF_SCAL + 2], s3c = ws[OFF_SCAL + 3];
        const float4 x4 = *(const float4*)(x + (size_t)(row0 + wv) * NC + 4 * lane);
        *(float4*)(xs + wv * NC + 4 * lane) = x4;
        float a = (x4.x + x4.y) + (x4.z + x4.w);
        float b = x4.x * x4.x + x4.y * x4.y + x4.z * x4.z + x4.w * x4.w;
        float cw = x4.x * wg4.x + x4.y * wg4.y + x4.z * wg4.z + x4.w * wg4.w;
        float dm = x4.x * m14.x + x4.y * m14.y + x4.z * m14.z + x4.w * m14.w;
        a = red16(a); b = red16(b); cw = red16(cw); dm = red16(dm);
        #pragma unroll
        for (int s = 16; s < 64; s <<= 1) {
            a += __shfl_xor(a, s, 64); b += __shfl_xor(b, s, 64);
            cw += __shfl_xor(cw, s, 64); dm += __shfl_xor(dm, s, 64);
        }
        mu_r = a * (1.f / NC);
        const float var = b * (1.f / NC) - mu_r * mu_r;
        rstd_r = rsqrtf(var + LNEPS);
        cst_r = rstd_r * (cw - mu_r * s0) + s1c;
        sg_r  = rstd_r * (dm - mu_r * s2c) + s3c;
    }
    __syncthreads();

    // ---- Phase 1: GEMV partials. Wave wv covers c in [64wv,64wv+64); output j = 4*lane+0..3 ----
    {
        float acc[RB][4];
        #pragma unroll
        for (int r = 0; r < RB; ++r) { acc[r][0] = acc[r][1] = acc[r][2] = acc[r][3] = 0.f; }
        const float* Mt = ws + OFF_MT;
        const int cb = 64 * wv;
        #pragma unroll 2
        for (int cc = 0; cc < 64; cc += 4) {
            const int c = cb + cc;
            const float4 m0  = *(const float4*)(Mt + (c + 0) * NC + 4 * lane);
            const float4 m1v = *(const float4*)(Mt + (c + 1) * NC + 4 * lane);
            const float4 m2  = *(const float4*)(Mt + (c + 2) * NC + 4 * lane);
            const float4 m3  = *(const float4*)(Mt + (c + 3) * NC + 4 * lane);
            #pragma unroll
            for (int r = 0; r < RB; ++r) {
                const float4 xv = *(const float4*)(xs + r * NC + c);  // broadcast
                acc[r][0] = fmaf(xv.x, m0.x, fmaf(xv.y, m1v.x, fmaf(xv.z, m2.x, fmaf(xv.w, m3.x, acc[r][0]))));
                acc[r][1] = fmaf(xv.x, m0.y, fmaf(xv.y, m1v.y, fmaf(xv.z, m2.y, fmaf(xv.w, m3.y, acc[r][1]))));
                acc[r][2] = fmaf(xv.x, m0.z, fmaf(xv.y, m1v.z, fmaf(xv.z, m2.z, fmaf(xv.w, m3.z, acc[r][2]))));
                acc[r][3] = fmaf(xv.x, m0.w, fmaf(xv.y, m1v.w, fmaf(xv.z, m2.w, fmaf(xv.w, m3.w, acc[r][3]))));
            }
        }
        #pragma unroll
        for (int r = 0; r < RB; ++r) {
            float4 o; o.x = acc[r][0]; o.y = acc[r][1]; o.z = acc[r][2]; o.w = acc[r][3];
            *(float4*)(tp + (wv * RB + r) * NC + 4 * lane) = o;
        }
    }
    __syncthreads();

    // ---- Phase 2: combine partials for own row -> gp into xs[wv] (x is dead; wave-local) ----
    {
        const float4 u4 = *(const float4*)(ws + OFF_UVEC + 4 * lane);
        const float4 v4 = *(const float4*)(ws + OFF_VV + 4 * lane);
        const float4 t0 = *(const float4*)(tp + (0 * RB + wv) * NC + 4 * lane);
        const float4 t1 = *(const float4*)(tp + (1 * RB + wv) * NC + 4 * lane);
        const float4 t2 = *(const float4*)(tp + (2 * RB + wv) * NC + 4 * lane);
        const float4 t3 = *(const float4*)(tp + (3 * RB + wv) * NC + 4 * lane);
        float4 gp;
        gp.x = rstd_r * ((t0.x + t1.x + t2.x + t3.x) - mu_r * u4.x) + v4.x;
        gp.y = rstd_r * ((t0.y + t1.y + t2.y + t3.y) - mu_r * u4.y) + v4.y;
        gp.z = rstd_r * ((t0.z + t1.z + t2.z + t3.z) - mu_r * u4.z) + v4.z;
        gp.w = rstd_r * ((t0.w + t1.w + t2.w + t3.w) - mu_r * u4.w) + v4.w;
        *(float4*)(xs + wv * NC + 4 * lane) = gp;
    }
    // no barrier: phase 3 reads only this wave's xs row

    // ---- Phase 3: stream own row. 2 halves of 32 lanes; half h handles keys 16h..16h+15.
    //      8 floats/lane/key, 2-slot pipeline, DPP+1-shfl reduce. ~50 VGPR target.
    {
        const int half = lane >> 5;
        const int i = lane & 31;
        const int sig = (lane & 15) + 16 * half;   // key this lane represents (2 lanes/key: l, l^16)
        const size_t row = (size_t)row0 + wv;
        const float* gl = xs + wv * NC;
        const vfloat4 gA = *(const vfloat4*)(gl + 4 * i);         // c = 4i   (0..127)
        const vfloat4 gB = *(const vfloat4*)(gl + 128 + 4 * i);   // c = 128+4i
        const float cst = cst_r, sg = sg_r;
        const float* kb0 = y + row * (size_t)(NN * NC) + (16 * half) * NC + 4 * i;
        const float zv = z[row * NN + sig];
        float dv = 0.f;
        vfloat4 a0, b0, a1, b1;

#define LOADS(S, T) \
        a##S = *(const vfloat4*)(kb0 + (T) * NC); \
        b##S = *(const vfloat4*)(kb0 + (T) * NC + 128);

#define REDK(S, T) { \
        float s1 = ((a##S.x + a##S.y) + (a##S.z + a##S.w)) + ((b##S.x + b##S.y) + (b##S.z + b##S.w)); \
        float s2 = a##S.x*a##S.x + a##S.y*a##S.y + a##S.z*a##S.z + a##S.w*a##S.w \
                 + b##S.x*b##S.x + b##S.y*b##S.y + b##S.z*b##S.z + b##S.w*b##S.w; \
        float s3 = a##S.x*gA.x + a##S.y*gA.y + a##S.z*gA.z + a##S.w*gA.w \
                 + b##S.x*gB.x + b##S.y*gB.y + b##S.z*gB.z + b##S.w*gB.w; \
        s1 = red16(s1); s2 = red16(s2); s3 = red16(s3); \
        s1 += __shfl_xor(s1, 16, 64); \
        s2 += __shfl_xor(s2, 16, 64); \
        s3 += __shfl_xor(s3, 16, 64); \
        const float mun = s1 * (1.f / NC); \
        const float varn = s2 * (1.f / NC) - mun * mun; \
        const float rsd = rsqrtf(varn + LNEPS); \
        const float dt = SCALE * (rsd * (s3 - mun * sg) + cst); \
        dv = ((lane & 15) == (T)) ? dt : dv; }

        LOADS(0, 0) LOADS(1, 1)
        REDK(0, 0)  LOADS(0, 2)
        REDK(1, 1)  LOADS(1, 3)
        REDK(0, 2)  LOADS(0, 4)
        REDK(1, 3)  LOADS(1, 5)
        REDK(0, 4)  LOADS(0, 6)
        REDK(1, 5)  LOADS(1, 7)
        REDK(0, 6)  LOADS(0, 8)
        REDK(1, 7)  LOADS(1, 9)
        REDK(0, 8)  LOADS(0, 10)
        REDK(1, 9)  LOADS(1, 11)
        REDK(0, 10) LOADS(0, 12)
        REDK(1, 11) LOADS(1, 13)
        REDK(0, 12) LOADS(0, 14)
        REDK(1, 13) LOADS(1, 15)
        REDK(0, 14) REDK(1, 15)
#undef LOADS
#undef REDK

        // softmax over 32 keys: folds over masks {1,2,4,8,32}; mask 16 skipped
        // (lanes l, l^16 hold the same key). Covers each key exactly once.
        float mx = dv;
        mx = fmaxf(mx, __shfl_xor(mx, 1, 64));
        mx = fmaxf(mx, __shfl_xor(mx, 2, 64));
        mx = fmaxf(mx, __shfl_xor(mx, 4, 64));
        mx = fmaxf(mx, __shfl_xor(mx, 8, 64));
        mx = fmaxf(mx, __shfl_xor(mx, 32, 64));
        const float e = __expf(dv - mx);
        float num = e * zv, den = e;
        num += __shfl_xor(num, 1, 64);  den += __shfl_xor(den, 1, 64);
        num += __shfl_xor(num, 2, 64);  den += __shfl_xor(den, 2, 64);
        num += __shfl_xor(num, 4, 64);  den += __shfl_xor(den, 4, 64);
        num += __shfl_xor(num, 8, 64);  den += __shfl_xor(den, 8, 64);
        num += __shfl_xor(num, 32, 64); den += __shfl_xor(den, 32, 64);
        if (lane == 0) out[row] = num / den;
    }
}

extern "C" void kernel_launch(void* const* d_in, const int* in_sizes, int n_in,
                              void* d_out, int out_size, void* d_ws, size_t ws_size,
                              hipStream_t stream) {
    const float* x  = (const float*)d_in[0];
    const float* y  = (const float*)d_in[1];
    const float* z  = (const float*)d_in[2];
    const float* qg = (const float*)d_in[3];
    const float* qb = (const float*)d_in[4];
    const float* Wq = (const float*)d_in[5];
    const float* bq = (const float*)d_in[6];
    const float* kg = (const float*)d_in[7];
    const float* kb = (const float*)d_in[8];
    const float* Wk = (const float*)d_in[9];
    const float* bk = (const float*)d_in[10];
    float* out = (float*)d_out;
    float* ws = (float*)d_ws;

    ca_prep_a<<<NC, 256, 0, stream>>>(Wq, Wk, qg, qb, kg, ws);
    ca_prep_b<<<1, 256, 0, stream>>>(Wq, Wk, qg, qb, kg, kb, bq, bk, ws);
    ca_main<<<NROWS / RB, 256, 0, stream>>>(x, y, z, ws, out);
}

// Round 12
// 150.099 us; speedup vs baseline: 1.0333x; 1.0333x over previous
//
#include <hip/hip_runtime.h>
#include <math.h>

#define NROWS 16384   // B*M
#define NN 32
#define NC 256
#define ND 128
#define RB 8          // rows per block
#define LNEPS 1e-5f
#define SCALE 0.08838834764831845f  // 1/sqrt(128)

typedef float vfloat4 __attribute__((ext_vector_type(4)));

// workspace float offsets
#define OFF_MT   0                      // Mt[c*256+j] = M''[j,c]   (65536)
#define OFF_UVEC 65536                  // uvec_j = sum_c M''[j,c]  (256)
#define OFF_VV   65792                  // vv_j                     (256)
#define OFF_M1   66048                  // m1_c = sum_j M''[j,c]    (256)
#define OFF_WG   66304                  // wg_c = qgamma_c * w_c    (256)
#define OFF_SCAL 66560                  // [sgw, sbw_full, su, svv] (8)

// Sum across each 16-lane row via DPP row_ror (VALU, ~4cy/step; no DS pipe).
// After the 4 rotation-doubling steps every lane holds its 16-lane row total.
__device__ __forceinline__ float red16(float v) {
    int t;
    t = __builtin_amdgcn_update_dpp(0, __float_as_int(v), 0x121, 0xf, 0xf, false); // row_ror:1
    v += __int_as_float(t);
    t = __builtin_amdgcn_update_dpp(0, __float_as_int(v), 0x122, 0xf, 0xf, false); // row_ror:2
    v += __int_as_float(t);
    t = __builtin_amdgcn_update_dpp(0, __float_as_int(v), 0x124, 0xf, 0xf, false); // row_ror:4
    v += __int_as_float(t);
    t = __builtin_amdgcn_update_dpp(0, __float_as_int(v), 0x128, 0xf, 0xf, false); // row_ror:8
    v += __int_as_float(t);
    return v;
}

// ---------------- K0a: M''[j,c] = kg_j*qg_c*sum_d Wk[j,d]Wq[c,d]; uvec, vv(part) ----------------
__global__ __launch_bounds__(256)
void ca_prep_a(const float* __restrict__ Wq, const float* __restrict__ Wk,
               const float* __restrict__ qg, const float* __restrict__ qb,
               const float* __restrict__ kg, float* __restrict__ ws) {
    __shared__ __align__(16) float wkrow[ND];
    __shared__ float red[8];
    const int j = blockIdx.x;
    const int c = threadIdx.x;
    const int lane = c & 63, wv = c >> 6;
    if (c < ND / 4) *(float4*)(wkrow + 4 * c) = *(const float4*)(Wk + j * ND + 4 * c);
    __syncthreads();
    float m = 0.f;
    #pragma unroll 8
    for (int d = 0; d < ND; d += 4) {
        const float4 wq4 = *(const float4*)(Wq + c * ND + d);
        const float4 wk4 = *(const float4*)(wkrow + d);
        m += wq4.x * wk4.x + wq4.y * wk4.y + wq4.z * wk4.z + wq4.w * wk4.w;
    }
    const float kgj = kg[j];
    const float mpp = kgj * qg[c] * m;     // M''[j,c]
    ws[OFF_MT + c * NC + j] = mpp;         // transposed store
    float a = red16(mpp), b = red16(kgj * m * qb[c]);
    a += __shfl_xor(a, 16, 64); b += __shfl_xor(b, 16, 64);
    a += __shfl_xor(a, 32, 64); b += __shfl_xor(b, 32, 64);
    if (lane == 0) { red[wv] = a; red[4 + wv] = b; }
    __syncthreads();
    if (c == 0) {
        ws[OFF_UVEC + j] = red[0] + red[1] + red[2] + red[3];
        ws[OFF_VV + j]   = red[4] + red[5] + red[6] + red[7];
    }
}

// ---------------- K0b: m1, h, vv += kg*(Wk bq), wg, scalars ----------------
__global__ __launch_bounds__(256)
void ca_prep_b(const float* __restrict__ Wq, const float* __restrict__ Wk,
               const float* __restrict__ qg, const float* __restrict__ qb,
               const float* __restrict__ kg, const float* __restrict__ kb,
               const float* __restrict__ bq, const float* __restrict__ bk,
               float* __restrict__ ws) {
    __shared__ float h[ND];
    __shared__ float htmp[2][ND];
    __shared__ float red[16];
    const int t = threadIdx.x, lane = t & 63, wv = t >> 6;
    // m1_c = sum_j Mt[c*NC + j]  (contiguous per thread, L2-hot)
    {
        float s = 0.f;
        const float* mrow = ws + OFF_MT + t * NC;
        #pragma unroll 8
        for (int j2 = 0; j2 < NC; j2 += 4) {
            const float4 m4 = *(const float4*)(mrow + j2);
            s += (m4.x + m4.y) + (m4.z + m4.w);
        }
        ws[OFF_M1 + t] = s;
    }
    // h_d = bk_d + sum_j Wk[j,d]*kb_j  (two half-sums)
    {
        const int d = t & (ND - 1), half = t >> 7;
        float s = 0.f;
        #pragma unroll 8
        for (int j = half * 128; j < half * 128 + 128; ++j) s += Wk[j * ND + d] * kb[j];
        htmp[half][d] = s;
    }
    __syncthreads();
    if (t < ND) h[t] = bk[t] + htmp[0][t] + htmp[1][t];
    __syncthreads();
    // vv[j] += kg_j*(Wk bq)_j
    float vvj;
    {
        float s = 0.f;
        #pragma unroll 8
        for (int d = 0; d < ND; d += 4) {
            const float4 w4 = *(const float4*)(Wk + t * ND + d);
            const float4 b4 = *(const float4*)(bq + d);
            s += w4.x * b4.x + w4.y * b4.y + w4.z * b4.z + w4.w * b4.w;
        }
        vvj = ws[OFF_VV + t] + kg[t] * s;
        ws[OFF_VV + t] = vvj;
    }
    // w_c = Wq[c,:].h ; wg, scalar sums
    float w = 0.f;
    #pragma unroll 8
    for (int d = 0; d < ND; d += 4) {
        const float4 w4 = *(const float4*)(Wq + t * ND + d);
        w += w4.x * h[d] + w4.y * h[d + 1] + w4.z * h[d + 2] + w4.w * h[d + 3];
    }
    ws[OFF_WG + t] = qg[t] * w;
    float r0 = qg[t] * w;
    float r1 = qb[t] * w + ((t < ND) ? bq[t] * h[t] : 0.f);
    float r2 = ws[OFF_UVEC + t];
    float r3 = vvj;
    r0 = red16(r0); r1 = red16(r1); r2 = red16(r2); r3 = red16(r3);
    #pragma unroll
    for (int s = 16; s < 64; s <<= 1) {
        r0 += __shfl_xor(r0, s, 64); r1 += __shfl_xor(r1, s, 64);
        r2 += __shfl_xor(r2, s, 64); r3 += __shfl_xor(r3, s, 64);
    }
    if (lane == 0) { red[wv] = r0; red[4 + wv] = r1; red[8 + wv] = r2; red[12 + wv] = r3; }
    __syncthreads();
    if (t == 0) {
        ws[OFF_SCAL + 0] = red[0] + red[1] + red[2] + red[3];
        ws[OFF_SCAL + 1] = red[4] + red[5] + red[6] + red[7];
        ws[OFF_SCAL + 2] = red[8] + red[9] + red[10] + red[11];
        ws[OFF_SCAL + 3] = red[12] + red[13] + red[14] + red[15];
    }
}

// ---------------- Fused main: stats -> GEMV -> combine -> stream ----------------
__global__ __launch_bounds__(256, 4)
void ca_main(const float* __restrict__ x, const float* __restrict__ y,
             const float* __restrict__ z, const float* __restrict__ ws,
             float* __restrict__ out) {
    __shared__ __align__(16) float xs[RB * NC];       // 8 KB: raw x rows
    __shared__ __align__(16) float tp[4 * RB * NC];   // 32 KB: GEMV partials; tp[0] region reused for gp
    const int tid = threadIdx.x;
    const int lane = tid & 63;
    const int wv = tid >> 6;
    const int row0 = blockIdx.x * RB;

    float mu_[2], rstd_[2], cst_[2], sgr_[2];

    // ---- Phase 0: stats on x (4 reductions) + stage x to LDS ----
    {
        const float4 wg4 = *(const float4*)(ws + OFF_WG + 4 * lane);
        const float4 m14 = *(const float4*)(ws + OFF_M1 + 4 * lane);
        const float s0 = ws[OFF_SCAL + 0], s1c = ws[OFF_SCAL + 1];
        const float s2c = ws[OFF_SCAL + 2], s3c = ws[OFF_SCAL + 3];
        #pragma unroll
        for (int jj = 0; jj < 2; ++jj) {
            const int r = 2 * wv + jj;
            const float4 x4 = *(const float4*)(x + (size_t)(row0 + r) * NC + 4 * lane);
            *(float4*)(xs + r * NC + 4 * lane) = x4;
            float a = (x4.x + x4.y) + (x4.z + x4.w);
            float b = x4.x * x4.x + x4.y * x4.y + x4.z * x4.z + x4.w * x4.w;
            float cw = x4.x * wg4.x + x4.y * wg4.y + x4.z * wg4.z + x4.w * wg4.w;
            float dm = x4.x * m14.x + x4.y * m14.y + x4.z * m14.z + x4.w * m14.w;
            a = red16(a); b = red16(b); cw = red16(cw); dm = red16(dm);
            #pragma unroll
            for (int s = 16; s < 64; s <<= 1) {
                a += __shfl_xor(a, s, 64); b += __shfl_xor(b, s, 64);
                cw += __shfl_xor(cw, s, 64); dm += __shfl_xor(dm, s, 64);
            }
            const float mu = a * (1.f / NC);
            const float var = b * (1.f / NC) - mu * mu;
            const float rstd = rsqrtf(var + LNEPS);
            mu_[jj] = mu; rstd_[jj] = rstd;
            cst_[jj] = rstd * (cw - mu * s0) + s1c;
            sgr_[jj] = rstd * (dm - mu * s2c) + s3c;
        }
    }
    __syncthreads();

    // ---- Phase 1: GEMV partials. Wave wv covers c in [64wv,64wv+64); output j = 4*lane+0..3 ----
    {
        float acc[RB][4];
        #pragma unroll
        for (int r = 0; r < RB; ++r) { acc[r][0] = acc[r][1] = acc[r][2] = acc[r][3] = 0.f; }
        const float* Mt = ws + OFF_MT;
        const int cb = 64 * wv;
        #pragma unroll 2
        for (int cc = 0; cc < 64; cc += 4) {
            const int c = cb + cc;
            const float4 m0  = *(const float4*)(Mt + (c + 0) * NC + 4 * lane);
            const float4 m1v = *(const float4*)(Mt + (c + 1) * NC + 4 * lane);
            const float4 m2  = *(const float4*)(Mt + (c + 2) * NC + 4 * lane);
            const float4 m3  = *(const float4*)(Mt + (c + 3) * NC + 4 * lane);
            #pragma unroll
            for (int r = 0; r < RB; ++r) {
                const float4 xv = *(const float4*)(xs + r * NC + c);  // broadcast
                acc[r][0] = fmaf(xv.x, m0.x, fmaf(xv.y, m1v.x, fmaf(xv.z, m2.x, fmaf(xv.w, m3.x, acc[r][0]))));
                acc[r][1] = fmaf(xv.x, m0.y, fmaf(xv.y, m1v.y, fmaf(xv.z, m2.y, fmaf(xv.w, m3.y, acc[r][1]))));
                acc[r][2] = fmaf(xv.x, m0.z, fmaf(xv.y, m1v.z, fmaf(xv.z, m2.z, fmaf(xv.w, m3.z, acc[r][2]))));
                acc[r][3] = fmaf(xv.x, m0.w, fmaf(xv.y, m1v.w, fmaf(xv.z, m2.w, fmaf(xv.w, m3.w, acc[r][3]))));
            }
        }
        #pragma unroll
        for (int r = 0; r < RB; ++r) {
            float4 o; o.x = acc[r][0]; o.y = acc[r][1]; o.z = acc[r][2]; o.w = acc[r][3];
            *(float4*)(tp + (wv * RB + r) * NC + 4 * lane) = o;
        }
    }
    __syncthreads();

    // ---- Phase 2: combine partials -> gp for this wave's rows; stash gp in tp[0] region ----
    {
        const float4 u4 = *(const float4*)(ws + OFF_UVEC + 4 * lane);
        const float4 v4 = *(const float4*)(ws + OFF_VV + 4 * lane);
        #pragma unroll
        for (int jj = 0; jj < 2; ++jj) {
            const int r = 2 * wv + jj;
            const float4 t0 = *(const float4*)(tp + (0 * RB + r) * NC + 4 * lane);
            const float4 t1 = *(const float4*)(tp + (1 * RB + r) * NC + 4 * lane);
            const float4 t2 = *(const float4*)(tp + (2 * RB + r) * NC + 4 * lane);
            const float4 t3 = *(const float4*)(tp + (3 * RB + r) * NC + 4 * lane);
            const float rstd = rstd_[jj], mu = mu_[jj];
            float4 gp;
            gp.x = rstd * ((t0.x + t1.x + t2.x + t3.x) - mu * u4.x) + v4.x;
            gp.y = rstd * ((t0.y + t1.y + t2.y + t3.y) - mu * u4.y) + v4.y;
            gp.z = rstd * ((t0.z + t1.z + t2.z + t3.z) - mu * u4.z) + v4.z;
            gp.w = rstd * ((t0.w + t1.w + t2.w + t3.w) - mu * u4.w) + v4.w;
            // rows are wave-exclusive in tp[0] region: no barrier needed before/after
            *(float4*)(tp + r * NC + 4 * lane) = gp;
        }
    }

    // ---- Phase 3: stream y. 4 groups of 16 lanes; group g handles keys 8g..8g+7.
    //      4-slot load pipeline; per-key reduce entirely on VALU via DPP row_ror.
    {
        const int g = lane >> 4;
        const int i = lane & 15;
        const int sig = 8 * g + (lane & 7);   // key this lane represents in softmax (2 lanes/key)
        #pragma unroll 1
        for (int jj = 0; jj < 2; ++jj) {
            const int r = 2 * wv + jj;
            const size_t row = (size_t)row0 + r;
            const float* gl = tp + r * NC + 4 * i;
            const vfloat4 g0 = *(const vfloat4*)(gl + 0);
            const vfloat4 g1 = *(const vfloat4*)(gl + 64);
            const vfloat4 g2 = *(const vfloat4*)(gl + 128);
            const vfloat4 g3 = *(const vfloat4*)(gl + 192);
            const float cst = cst_[jj], sg = sgr_[jj];
            const float* kb0 = y + row * (size_t)(NN * NC) + (8 * g) * NC + 4 * i;
            const float zv = z[row * NN + sig];
            float dv = 0.f;
            vfloat4 ya0, yb0, yc0, yd0, ya1, yb1, yc1, yd1;
            vfloat4 ya2, yb2, yc2, yd2, ya3, yb3, yc3, yd3;

#define LOADS(S, K) \
            ya##S = *(const vfloat4*)(kb0 + (K) * NC + 0); \
            yb##S = *(const vfloat4*)(kb0 + (K) * NC + 64); \
            yc##S = *(const vfloat4*)(kb0 + (K) * NC + 128); \
            yd##S = *(const vfloat4*)(kb0 + (K) * NC + 192);

#define REDK(S, K) { \
            float s1 = (((ya##S.x + ya##S.y) + (ya##S.z + ya##S.w)) + ((yb##S.x + yb##S.y) + (yb##S.z + yb##S.w))) \
                     + (((yc##S.x + yc##S.y) + (yc##S.z + yc##S.w)) + ((yd##S.x + yd##S.y) + (yd##S.z + yd##S.w))); \
            float s2 = ya##S.x*ya##S.x + ya##S.y*ya##S.y + ya##S.z*ya##S.z + ya##S.w*ya##S.w \
                     + yb##S.x*yb##S.x + yb##S.y*yb##S.y + yb##S.z*yb##S.z + yb##S.w*yb##S.w \
                     + yc##S.x*yc##S.x + yc##S.y*yc##S.y + yc##S.z*yc##S.z + yc##S.w*yc##S.w \
                     + yd##S.x*yd##S.x + yd##S.y*yd##S.y + yd##S.z*yd##S.z + yd##S.w*yd##S.w; \
            float s3 = ya##S.x*g0.x + ya##S.y*g0.y + ya##S.z*g0.z + ya##S.w*g0.w \
                     + yb##S.x*g1.x + yb##S.y*g1.y + yb##S.z*g1.z + yb##S.w*g1.w \
                     + yc##S.x*g2.x + yc##S.y*g2.y + yc##S.z*g2.z + yc##S.w*g2.w \
                     + yd##S.x*g3.x + yd##S.y*g3.y + yd##S.z*g3.z + yd##S.w*g3.w; \
            s1 = red16(s1); s2 = red16(s2); s3 = red16(s3); \
            const float mun = s1 * (1.f / NC); \
            const float varn = s2 * (1.f / NC) - mun * mun; \
            const float rsd = rsqrtf(varn + LNEPS); \
            const float dt = SCALE * (rsd * (s3 - mun * sg) + cst); \
            dv = ((lane & 7) == (K)) ? dt : dv; }

            LOADS(0, 0) LOADS(1, 1) LOADS(2, 2) LOADS(3, 3)
            REDK(0, 0) LOADS(0, 4)
            REDK(1, 1) LOADS(1, 5)
            REDK(2, 2) LOADS(2, 6)
            REDK(3, 3) LOADS(3, 7)
            REDK(0, 4) REDK(1, 5) REDK(2, 6) REDK(3, 7)
#undef LOADS
#undef REDK

            // softmax over 32 keys: 5 folds (mask 8 skipped — lanes l, l^8 hold same key)
            float mx = dv;
            mx = fmaxf(mx, __shfl_xor(mx, 1, 64));
            mx = fmaxf(mx, __shfl_xor(mx, 2, 64));
            mx = fmaxf(mx, __shfl_xor(mx, 4, 64));
            mx = fmaxf(mx, __shfl_xor(mx, 16, 64));
            mx = fmaxf(mx, __shfl_xor(mx, 32, 64));
            const float e = __expf(dv - mx);
            float num = e * zv, den = e;
            num += __shfl_xor(num, 1, 64);  den += __shfl_xor(den, 1, 64);
            num += __shfl_xor(num, 2, 64);  den += __shfl_xor(den, 2, 64);
            num += __shfl_xor(num, 4, 64);  den += __shfl_xor(den, 4, 64);
            num += __shfl_xor(num, 16, 64); den += __shfl_xor(den, 16, 64);
            num += __shfl_xor(num, 32, 64); den += __shfl_xor(den, 32, 64);
            if (lane == 0) out[row] = num / den;
        }
    }
}

extern "C" void kernel_launch(void* const* d_in, const int* in_sizes, int n_in,
                              void* d_out, int out_size, void* d_ws, size_t ws_size,
                              hipStream_t stream) {
    const float* x  = (const float*)d_in[0];
    const float* y  = (const float*)d_in[1];
    const float* z  = (const float*)d_in[2];
    const float* qg = (const float*)d_in[3];
    const float* qb = (const float*)d_in[4];
    const float* Wq = (const float*)d_in[5];
    const float* bq = (const float*)d_in[6];
    const float* kg = (const float*)d_in[7];
    const float* kb = (const float*)d_in[8];
    const float* Wk = (const float*)d_in[9];
    const float* bk = (const float*)d_in[10];
    float* out = (float*)d_out;
    float* ws = (float*)d_ws;

    ca_prep_a<<<NC, 256, 0, stream>>>(Wq, Wk, qg, qb, kg, ws);
    ca_prep_b<<<1, 256, 0, stream>>>(Wq, Wk, qg, qb, kg, kb, bq, bk, ws);
    ca_main<<<NROWS / RB, 256, 0, stream>>>(x, y, z, ws, out);
}